// Round 1
// baseline (141.123 us; speedup 1.0000x reference)
//
#include <hip/hip_runtime.h>

namespace {

constexpr int S = 128;   // fine bins per row
constexpr int P = 64;    // proposal bins per row
constexpr float EPS = 1.1920928955078125e-07f;  // np.finfo(np.float32).eps

// One 64-lane wave per row; 4 waves (rows) per 256-thread block.
// LDS per wave: t_hat padded to 128 (sentinel 2.0f) + cy1[65].
__global__ __launch_bounds__(256) void proposal_loss_kernel(
    const float* __restrict__ t,      // [N, S+1]
    const float* __restrict__ w,      // [N, S]
    const float* __restrict__ t_hat,  // [N, P+1]
    const float* __restrict__ w_hat,  // [N, P]
    float* __restrict__ out)          // [N, S]
{
    const int wv   = threadIdx.x >> 6;   // wave id within block: 0..3
    const int lane = threadIdx.x & 63;
    const int row  = (blockIdx.x << 2) + wv;

    __shared__ float s_th[4][128];  // t_hat row, 65 valid + sentinels
    __shared__ float s_cy[4][66];   // cy1 row, 65 valid

    const float* th_row = t_hat + (size_t)row * (P + 1);
    const float* wh_row = w_hat + (size_t)row * P;

    // ---- stage t_hat into LDS, pad [65..127] with 2.0f (> any query) ----
    float th = th_row[lane];
    s_th[wv][lane] = th;
    s_th[wv][64 + lane] = (lane == 0) ? th_row[P] : 2.0f;

    // ---- cy1 = [0, cumsum(w_hat)] via wave-wide inclusive scan ----
    float wh  = wh_row[lane];
    float inc = wh;
    #pragma unroll
    for (int d = 1; d < 64; d <<= 1) {
        float o = __shfl_up(inc, d, 64);
        if (lane >= d) inc += o;
    }
    s_cy[wv][lane] = inc - wh;          // exclusive prefix
    if (lane == 63) s_cy[wv][P] = inc;  // total sum

    __syncthreads();  // all 4 waves valid (grid sized exactly), safe

    const float* tha = s_th[wv];
    const float* cya = s_cy[wv];

    const float* t_row = t + (size_t)row * (S + 1);
    const float* w_row = w + (size_t)row * S;
    float*       o_row = out + (size_t)row * S;

    // Each lane handles s = 2*lane and 2*lane+1.
    float2 tt = *reinterpret_cast<const float2*>(t_row + 2 * lane);
    float t0 = tt.x, t1 = tt.y;
    float t2 = __shfl_down(t0, 1, 64);      // next lane's t[2l] = t[2l+2]
    if (lane == 63) t2 = t_row[S];          // t[128]
    float2 ww = *reinterpret_cast<const float2*>(w_row + 2 * lane);

    // Branchless meta binary search over virtual size-128 sorted array.
    // Returns count of elements < v (lower bound). Queries v in (0,1),
    // tha[64]=1.0 and sentinels 2.0 guarantee pos <= 64.
    auto lb = [&](float v) {
        int pos = 0;
        #pragma unroll
        for (int st = 64; st > 0; st >>= 1)
            pos += (tha[pos + st - 1] < v) ? st : 0;
        return pos;
    };
    auto ub = [&](float v) {  // count of elements <= v (upper bound)
        int pos = 0;
        #pragma unroll
        for (int st = 64; st > 0; st >>= 1)
            pos += (tha[pos + st - 1] <= v) ? st : 0;
        return pos;
    };

    const int l0 = lb(t0);   // idx_left  at t[s]
    const int r1 = ub(t1);   // idx_right at t[s+1]
    const int l1 = lb(t1);
    const int r2 = ub(t2);

    const float wo0 = cya[r1] - cya[l0];
    const float wo1 = cya[r2] - cya[l1];

    const float d0 = fmaxf(0.0f, ww.x - wo0);
    const float d1 = fmaxf(0.0f, ww.y - wo1);
    float2 res;
    res.x = d0 * d0 / (ww.x + EPS);
    res.y = d1 * d1 / (ww.y + EPS);
    *reinterpret_cast<float2*>(o_row + 2 * lane) = res;
}

}  // namespace

extern "C" void kernel_launch(void* const* d_in, const int* in_sizes, int n_in,
                              void* d_out, int out_size, void* d_ws, size_t ws_size,
                              hipStream_t stream) {
    const float* t     = (const float*)d_in[0];
    const float* w     = (const float*)d_in[1];
    const float* t_hat = (const float*)d_in[2];
    const float* w_hat = (const float*)d_in[3];
    float* out = (float*)d_out;

    const int N = in_sizes[1] / S;  // 262144
    // N divisible by 4 -> every block has 4 full rows (syncthreads-safe).
    proposal_loss_kernel<<<N / 4, 256, 0, stream>>>(t, w, t_hat, w_hat, out);
}

// Round 2
// 100.203 us; speedup vs baseline: 1.4084x; 1.4084x over previous
//
#include <hip/hip_runtime.h>

namespace {

constexpr int S = 128;   // fine bins per row
constexpr int P = 64;    // proposal bins per row
constexpr float EPS = 1.1920928955078125e-07f;  // np.finfo(np.float32).eps

// Crossbar read: value of `v` from lane (byteaddr/4). Conflict-free always.
__device__ inline float bperm_f(int byteaddr, float v) {
    return __int_as_float(__builtin_amdgcn_ds_bpermute(byteaddr, __float_as_int(v)));
}

// One 64-lane wave per row, everything in registers via ds_bpermute.
// Lane l holds th1 = t_hat[l+1] and inc = cy1[l+1] (inclusive w_hat scan).
// lower_bound over the 64 inner entries t_hat[1..64]; since t in (0,1),
// t_hat[0]=0 and t_hat[64]=1, true lb index is in [1,64] -> 6 steps suffice.
// Byte offset convention: t_hat[i] / cy1[i] live at lane i-1 -> byte (i-1)*4.
__global__ __launch_bounds__(256) void proposal_loss_kernel(
    const float* __restrict__ t,      // [N, S+1]
    const float* __restrict__ w,      // [N, S]
    const float* __restrict__ t_hat,  // [N, P+1]
    const float* __restrict__ w_hat,  // [N, P]
    float* __restrict__ out)          // [N, S]
{
    const int wv   = threadIdx.x >> 6;
    const int lane = threadIdx.x & 63;
    const int row  = (blockIdx.x << 2) + wv;

    const float* t_row  = t     + (size_t)row * (S + 1);
    const float* w_row  = w     + (size_t)row * S;
    const float* th_row = t_hat + (size_t)row * (P + 1);
    const float* wh_row = w_hat + (size_t)row * P;
    float*       o_row  = out   + (size_t)row * S;

    // ---- loads (issue all early) ----
    const float th1 = th_row[lane + 1];                     // t_hat[lane+1]
    const float wh  = wh_row[lane];
    const float2 tt = *reinterpret_cast<const float2*>(t_row + 2 * lane);
    const float2 ww = *reinterpret_cast<const float2*>(w_row + 2 * lane);
    float tS = 0.0f;
    if (lane == 63) tS = t_row[S];                          // t[128] for lane 63

    // ---- inclusive scan of w_hat: inc(lane j) = cy1[j+1] ----
    float inc = wh;
    #pragma unroll
    for (int d = 1; d < 64; d <<= 1) {
        float o = __shfl_up(inc, d, 64);
        if (lane >= d) inc += o;
    }

    const float t0 = tt.x, t1 = tt.y;
    float t2 = __shfl_down(t0, 1, 64);                      // t[2l+2]
    if (lane == 63) t2 = tS;

    // Branchless 6-step lower_bound over t_hat[1..64] held in registers.
    // Returns byte offset b with lb_index = b/4 + 1 (lb in [1,64]).
    auto lb_byte = [&](float v) {
        int posb = 0;
        #pragma unroll
        for (int st = 32; st > 0; st >>= 1) {
            float p = bperm_f(posb + (st - 1) * 4, th1);    // t_hat[posb/4 + st]
            posb += (p < v) ? st * 4 : 0;
        }
        return posb;                                        // (lb-1)*4
    };

    const int b0 = lb_byte(t0);   // lb(t0)
    const int b1 = lb_byte(t1);   // lb(t1)
    const int b2 = lb_byte(t2);   // lb(t2)

    // ub fixup: ub = lb + (t_hat[lb] == v)
    const float q1 = bperm_f(b1, th1);
    const float q2 = bperm_f(b2, th1);
    const int r1b = b1 + ((q1 == t1) ? 4 : 0);
    const int r2b = b2 + ((q2 == t2) ? 4 : 0);

    // Gathers from the register-resident cy1 (cy1[i] at lane i-1 = byte (i-1)*4)
    const float cy_l0 = bperm_f(b0,  inc);
    const float cy_l1 = bperm_f(b1,  inc);
    const float cy_r1 = bperm_f(r1b, inc);
    const float cy_r2 = bperm_f(r2b, inc);

    const float wo0 = cy_r1 - cy_l0;   // w_outer[2l]
    const float wo1 = cy_r2 - cy_l1;   // w_outer[2l+1]

    const float d0 = fmaxf(0.0f, ww.x - wo0);
    const float d1 = fmaxf(0.0f, ww.y - wo1);
    float2 res;
    res.x = d0 * d0 * __builtin_amdgcn_rcpf(ww.x + EPS);
    res.y = d1 * d1 * __builtin_amdgcn_rcpf(ww.y + EPS);
    *reinterpret_cast<float2*>(o_row + 2 * lane) = res;
}

}  // namespace

extern "C" void kernel_launch(void* const* d_in, const int* in_sizes, int n_in,
                              void* d_out, int out_size, void* d_ws, size_t ws_size,
                              hipStream_t stream) {
    const float* t     = (const float*)d_in[0];
    const float* w     = (const float*)d_in[1];
    const float* t_hat = (const float*)d_in[2];
    const float* w_hat = (const float*)d_in[3];
    float* out = (float*)d_out;

    const int N = in_sizes[1] / S;  // 262144
    proposal_loss_kernel<<<N / 4, 256, 0, stream>>>(t, w, t_hat, w_hat, out);
}